// Round 6
// baseline (1321.170 us; speedup 1.0000x reference)
//
#include <hip/hip_runtime.h>

#define CIN 64
#define COUT 128
#define NB 32        // skip-stat buckets
#define NBLK 2048    // conv grid (multiple of 8)
#define LDT 132      // padded LDS row (dwords)

typedef __bf16 bf16x8 __attribute__((ext_vector_type(8)));
typedef float  f32x4  __attribute__((ext_vector_type(4)));

// ---------------------------------------------------------------------------
// Prep: features fp32 -> bf16 rows.
// ---------------------------------------------------------------------------
__global__ __launch_bounds__(256) void prep_feats_kernel(
    const float* __restrict__ feats, __bf16* __restrict__ fb, int total8)
{
    const int i = blockIdx.x * 256 + threadIdx.x;
    if (i >= total8) return;
    const int i8 = i * 8;
    const float4 x0 = *(const float4*)(feats + i8);
    const float4 x1 = *(const float4*)(feats + i8 + 4);
    bf16x8 v;
    v[0] = (__bf16)x0.x; v[1] = (__bf16)x0.y; v[2] = (__bf16)x0.z; v[3] = (__bf16)x0.w;
    v[4] = (__bf16)x1.x; v[5] = (__bf16)x1.y; v[6] = (__bf16)x1.z; v[7] = (__bf16)x1.w;
    *(bf16x8*)(fb + i8) = v;
}

// ---------------------------------------------------------------------------
// Prep: pack W_conv (9 taps) + W_skip into MFMA B-fragment layout.
// ---------------------------------------------------------------------------
__global__ __launch_bounds__(256) void prep_wfrag_kernel(
    const float* __restrict__ Wc, const float* __restrict__ Ws,
    __bf16* __restrict__ wf)
{
    const int id = blockIdx.x * 256 + threadIdx.x;
    if (id >= 160 * 64) return;
    const int f = id >> 6, lane = id & 63;
    const float* W;
    int r;
    if (f < 144) { W = Wc + (size_t)(f >> 4) * CIN * COUT; r = f & 15; }
    else         { W = Ws;                                  r = f - 144; }
    const int c = r >> 1, s = r & 1;
    const int kbase = s * 32 + (lane >> 4) * 8;
    const int col = c * 16 + (lane & 15);
    bf16x8 v;
#pragma unroll
    for (int j = 0; j < 8; ++j) v[j] = (__bf16)W[(size_t)(kbase + j) * COUT + col];
    *(bf16x8*)(wf + ((size_t)f * 64 + lane) * 8) = v;
}

// ---------------------------------------------------------------------------
// tap_in fill (= N sentinel) + m_split (batch boundary).
// ---------------------------------------------------------------------------
__global__ __launch_bounds__(256) void tap_fill_kernel(
    int* __restrict__ tap_in, int* __restrict__ msplit,
    const int* __restrict__ boo, int total, int N, int M)
{
    const int id = blockIdx.x * 256 + threadIdx.x;
    if (id < total) tap_in[id] = N;
    if (id == 0) {
        int lo = 0, hi = M;
        while (lo < hi) { const int mid = (lo + hi) >> 1; if (boo[mid] < 1) lo = mid + 1; else hi = mid; }
        msplit[0] = lo;
    }
}

__global__ __launch_bounds__(256) void tap_scatter_kernel(
    const int* __restrict__ cin_idx, const int* __restrict__ cout_idx,
    int* __restrict__ tap_in, int P, int M)
{
    const int e = blockIdx.x * 256 + threadIdx.x;
    const int k = blockIdx.y;
    if (e >= P) return;
    const int oo = cout_idx[(size_t)k * P + e];
    if (oo < M) tap_in[(size_t)k * M + oo] = cin_idx[(size_t)k * P + e];
}

__global__ __launch_bounds__(256) void inv_kernel(
    const int* __restrict__ sout, int* __restrict__ inv, int Ls)
{
    const int i = blockIdx.x * 256 + threadIdx.x;
    if (i < Ls) inv[sout[i]] = i;
}

// ---------------------------------------------------------------------------
// Conv as dense-K gather-GEMM; 16 rows per wave; XCD-chunked contiguous jobs;
// coalesced stores via per-wave LDS transpose; fused BN stats -> private slot.
// ---------------------------------------------------------------------------
__global__ __launch_bounds__(256, 3) void conv_mfma_kernel(
    const __bf16* __restrict__ fb,      // [N+1][CIN], row N = zeros
    const __bf16* __restrict__ wf,
    const int* __restrict__ tap_in,     // [9][M]
    const int* __restrict__ msplit_p,
    float* __restrict__ out,
    float* __restrict__ gstats,         // [NBLK][384]
    int N, int M, int njobs, int jpb)
{
    __shared__ float tile[4][16 * LDT];
    __shared__ float sred[3][4][128];
    const int t = threadIdx.x, lane = t & 63, wv = t >> 6;
    const int arow = lane & 15, apart = lane >> 4;
    const int msplit = msplit_p[0];

    // XCD-contiguous chunk mapping (blockIdx % 8 ~ XCD round-robin)
    const int chunk = (blockIdx.x & 7) * (gridDim.x >> 3) + (blockIdx.x >> 3);
    int jend = (chunk + 1) * jpb; if (jend > njobs) jend = njobs;

    float sA[8], qA[8], s0A[8];
#pragma unroll
    for (int c = 0; c < 8; ++c) { sA[c] = 0.f; qA[c] = 0.f; s0A[c] = 0.f; }

    float* T = tile[wv];

    for (int job = chunk * jpb + wv; job < jend; job += 4) {
        const int m0 = job * 16;
        const int mr = m0 + arow;

        f32x4 D[8];
#pragma unroll
        for (int c = 0; c < 8; ++c) D[c] = (f32x4){0.f, 0.f, 0.f, 0.f};

#pragma unroll
        for (int k = 0; k < 9; ++k) {
            const int idx = (mr < M) ? tap_in[(size_t)k * M + mr] : N;
            const __bf16* f0 = fb + (size_t)idx * CIN + apart * 8;
            const bf16x8 a0 = *(const bf16x8*)f0;
            const bf16x8 a1 = *(const bf16x8*)(f0 + 32);
            const __bf16* wb = wf + ((size_t)(k * 16) * 64 + lane) * 8;
#pragma unroll
            for (int c = 0; c < 8; ++c) {
                const bf16x8 b0 = *(const bf16x8*)(wb + (size_t)(c * 2 + 0) * 512);
                const bf16x8 b1 = *(const bf16x8*)(wb + (size_t)(c * 2 + 1) * 512);
                D[c] = __builtin_amdgcn_mfma_f32_16x16x32_bf16(a0, b0, D[c], 0, 0, 0);
                D[c] = __builtin_amdgcn_mfma_f32_16x16x32_bf16(a1, b1, D[c], 0, 0, 0);
            }
        }

        // stats + LDS transpose (D: col=c*16+arow, row=apart*4+j)
#pragma unroll
        for (int c = 0; c < 8; ++c) {
#pragma unroll
            for (int j = 0; j < 4; ++j) {
                const int r = apart * 4 + j;
                const int m = m0 + r;
                float v = D[c][j];
                if (m >= M) v = 0.f;
                T[r * LDT + c * 16 + arow] = v;
                sA[c] += v; qA[c] += v * v;
                if (m < msplit) s0A[c] += v;
            }
        }
        asm volatile("s_waitcnt lgkmcnt(0)" ::: "memory");

        // coalesced read-back + store: 2 rows / instruction, 1KB contiguous
#pragma unroll
        for (int i = 0; i < 8; ++i) {
            const int r = i * 2 + (lane >> 5);
            const int cd = (lane & 31) * 4;          // dword offset in row
            const f32x4 v = *(const f32x4*)&T[r * LDT + cd];
            const int m = m0 + r;
            if (m < M) *(f32x4*)(out + (size_t)m * COUT + cd) = v;
        }
    }

    // stats: shuffle over apart (lane bits 4,5) -> LDS over waves -> slot
#pragma unroll
    for (int c = 0; c < 8; ++c) {
        sA[c]  += __shfl_xor(sA[c], 16);  sA[c]  += __shfl_xor(sA[c], 32);
        s0A[c] += __shfl_xor(s0A[c], 16); s0A[c] += __shfl_xor(s0A[c], 32);
        qA[c]  += __shfl_xor(qA[c], 16);  qA[c]  += __shfl_xor(qA[c], 32);
    }
    if (apart == 0) {
#pragma unroll
        for (int c = 0; c < 8; ++c) {
            const int col = c * 16 + arow;
            sred[0][wv][col] = s0A[c];
            sred[1][wv][col] = sA[c] - s0A[c];
            sred[2][wv][col] = qA[c];
        }
    }
    __syncthreads();
    if (t < 128) {
        float* gs = gstats + (size_t)blockIdx.x * 384;
        gs[t]       = sred[0][0][t] + sred[0][1][t] + sred[0][2][t] + sred[0][3][t];
        gs[128 + t] = sred[1][0][t] + sred[1][1][t] + sred[1][2][t] + sred[1][3][t];
        gs[256 + t] = sred[2][0][t] + sred[2][1][t] + sred[2][2][t] + sred[2][3][t];
    }
}

// ---------------------------------------------------------------------------
// Reduce gstats[NBLK][384] -> gsum[384].
// ---------------------------------------------------------------------------
__global__ __launch_bounds__(256) void reduce_gstats_kernel(
    const float* __restrict__ gstats, float* __restrict__ gsum, int nblk)
{
    __shared__ float red[256];
    const int sc = blockIdx.x;
    float s = 0.f;
    for (int b = threadIdx.x; b < nblk; b += 256) s += gstats[(size_t)b * 384 + sc];
    red[threadIdx.x] = s;
    __syncthreads();
    for (int st = 128; st > 0; st >>= 1) {
        if (threadIdx.x < st) red[threadIdx.x] += red[threadIdx.x + st];
        __syncthreads();
    }
    if (threadIdx.x == 0) gsum[sc] = red[0];
}

// ---------------------------------------------------------------------------
// Skip path via MFMA, column-split waves, bucketed stat atomics.
// ---------------------------------------------------------------------------
__global__ __launch_bounds__(256, 2) void skip_mfma_kernel(
    const __bf16* __restrict__ fb, const __bf16* __restrict__ wf,
    const int* __restrict__ sin_idx,
    float* __restrict__ G, float* __restrict__ stats, int Ls)
{
    __shared__ float sk[2][COUT];
    const int t = threadIdx.x, lane = t & 63, wv = t >> 6;
    const int arow = lane & 15, apart = lane >> 4;

    const __bf16* wk = wf + ((size_t)144 * 64 + lane) * 8;
    const bf16x8 b00 = *(const bf16x8*)(wk + (size_t)(wv * 4 + 0) * 512);
    const bf16x8 b01 = *(const bf16x8*)(wk + (size_t)(wv * 4 + 1) * 512);
    const bf16x8 b10 = *(const bf16x8*)(wk + (size_t)(wv * 4 + 2) * 512);
    const bf16x8 b11 = *(const bf16x8*)(wk + (size_t)(wv * 4 + 3) * 512);
    const int colA = wv * 32 + arow;
    const int colB = colA + 16;

    float s1A = 0.f, s2A = 0.f, s1B = 0.f, s2B = 0.f;
    const int ngroups = (Ls + 15) >> 4;
    for (int g = blockIdx.x; g < ngroups; g += gridDim.x) {
        const int e0 = g * 16;
        const int ea = e0 + arow;
        const int ii = (ea < Ls) ? sin_idx[ea] : 0;
        const __bf16* fr = fb + (size_t)ii * CIN + apart * 8;
        const bf16x8 a0 = *(const bf16x8*)fr;
        const bf16x8 a1 = *(const bf16x8*)(fr + 32);

        f32x4 dA = {0.f,0.f,0.f,0.f};
        f32x4 dB = {0.f,0.f,0.f,0.f};
        dA = __builtin_amdgcn_mfma_f32_16x16x32_bf16(a0, b00, dA, 0, 0, 0);
        dA = __builtin_amdgcn_mfma_f32_16x16x32_bf16(a1, b01, dA, 0, 0, 0);
        dB = __builtin_amdgcn_mfma_f32_16x16x32_bf16(a0, b10, dB, 0, 0, 0);
        dB = __builtin_amdgcn_mfma_f32_16x16x32_bf16(a1, b11, dB, 0, 0, 0);

        const int er = e0 + apart * 4;
#pragma unroll
        for (int j = 0; j < 4; ++j) {
            if (er + j < Ls) {
                const float vA = dA[j], vB = dB[j];
                G[(size_t)(er + j) * COUT + colA] = vA;
                G[(size_t)(er + j) * COUT + colB] = vB;
                s1A += vA; s2A += vA * vA;
                s1B += vB; s2B += vB * vB;
            }
        }
    }
    s1A += __shfl_xor(s1A, 16); s1A += __shfl_xor(s1A, 32);
    s2A += __shfl_xor(s2A, 16); s2A += __shfl_xor(s2A, 32);
    s1B += __shfl_xor(s1B, 16); s1B += __shfl_xor(s1B, 32);
    s2B += __shfl_xor(s2B, 16); s2B += __shfl_xor(s2B, 32);
    if (apart == 0) {
        sk[0][colA] = s1A; sk[0][colB] = s1B;
        sk[1][colA] = s2A; sk[1][colB] = s2B;
    }
    __syncthreads();
    float* bucket = stats + (size_t)(blockIdx.x & (NB - 1)) * 640;
    if (t < 128) {
        atomicAdd(&bucket[384 + t], sk[0][t]);
        atomicAdd(&bucket[512 + t], sk[1][t]);
    }
}

// ---------------------------------------------------------------------------
// Single-block: combine gsum + skip buckets, BN params, SE MLP.
// ---------------------------------------------------------------------------
__global__ __launch_bounds__(128) void params_kernel(
    const float* __restrict__ gsum,
    const float* __restrict__ stats,
    const int* __restrict__ msplit_p,
    const float* __restrict__ gamma, const float* __restrict__ beta,
    const float* __restrict__ sgamma, const float* __restrict__ sbeta,
    const float* __restrict__ fc1, const float* __restrict__ fc2,
    float* __restrict__ scale, float* __restrict__ shift,
    float* __restrict__ sscale, float* __restrict__ sshift,
    float* __restrict__ attn,
    int Ls, int M)
{
    __shared__ float desc[2][COUT];
    __shared__ float hid[2][8];
    const int ch = threadIdx.x;

    const float s0 = gsum[ch], s1 = gsum[128 + ch], q = gsum[256 + ch];
    float ss = 0.f, sq = 0.f;
    for (int b = 0; b < NB; ++b) {
        const float* st = stats + (size_t)b * 640;
        ss += st[384 + ch]; sq += st[512 + ch];
    }

    const float c0 = (float)msplit_p[0], c1 = (float)M - c0;
    const float Mf = (float)M;
    const float mu  = (s0 + s1) / Mf;
    const float var = q / Mf - mu * mu;
    const float rs  = rsqrtf(var + 1e-5f);
    const float sc  = rs * gamma[ch];
    const float sh  = beta[ch] - mu * sc;
    scale[ch] = sc;
    shift[ch] = sh;
    desc[0][ch] = (s0 / c0) * sc + sh;
    desc[1][ch] = (s1 / c1) * sc + sh;

    const float lsf  = (float)Ls;
    const float mus  = ss / lsf;
    const float vars = sq / lsf - mus * mus;
    const float rss  = rsqrtf(vars + 1e-5f);
    const float ssc  = rss * sgamma[ch];
    sscale[ch] = ssc;
    sshift[ch] = sbeta[ch] - mus * ssc;

    __syncthreads();
    if (ch < 16) {
        const int b = ch >> 3, h = ch & 7;
        float a = 0.f;
        for (int c = 0; c < COUT; ++c) a += desc[b][c] * fc1[c * 8 + h];
        hid[b][h] = fmaxf(a, 0.f);
    }
    __syncthreads();
    for (int b = 0; b < 2; ++b) {
        float a = 0.f;
        for (int h = 0; h < 8; ++h) a += hid[b][h] * fc2[h * COUT + ch];
        attn[b * COUT + ch] = 1.f / (1.f + expf(-a));
    }
}

// ---------------------------------------------------------------------------
// Epilogue: out = relu(bn(x)*attn[b] + bn_skip(G[inv])), float4-vectorized.
// ---------------------------------------------------------------------------
__global__ __launch_bounds__(256) void final_kernel(
    float* __restrict__ out,
    const float* __restrict__ G,
    const int* __restrict__ inv_skip,
    const int* __restrict__ batch_of_out,
    const float* __restrict__ scale, const float* __restrict__ shift,
    const float* __restrict__ sscale, const float* __restrict__ sshift,
    const float* __restrict__ attn,
    int M)
{
    const int t  = threadIdx.x;
    const int c4 = (t & 31) * 4;
    const int rw = t >> 5;
    const float4 sc  = *(const float4*)&scale[c4];
    const float4 sh  = *(const float4*)&shift[c4];
    const float4 ssc = *(const float4*)&sscale[c4];
    const float4 ssh = *(const float4*)&sshift[c4];
    const float4 at0 = *(const float4*)&attn[c4];
    const float4 at1 = *(const float4*)&attn[COUT + c4];

    for (int m = blockIdx.x * 8 + rw; m < M; m += gridDim.x * 8) {
        const float4 x = *(const float4*)&out[(size_t)m * COUT + c4];
        const int b = batch_of_out[m];
        const int j = inv_skip[m];
        const float4 av = b ? at1 : at0;
        float4 y;
        y.x = (x.x * sc.x + sh.x) * av.x;
        y.y = (x.y * sc.y + sh.y) * av.y;
        y.z = (x.z * sc.z + sh.z) * av.z;
        y.w = (x.w * sc.w + sh.w) * av.w;
        if (j >= 0) {
            const float4 g = *(const float4*)&G[(size_t)j * COUT + c4];
            y.x += g.x * ssc.x + ssh.x;
            y.y += g.y * ssc.y + ssh.y;
            y.z += g.z * ssc.z + ssh.z;
            y.w += g.w * ssc.w + ssh.w;
        }
        y.x = y.x > 0.f ? y.x : 0.f;
        y.y = y.y > 0.f ? y.y : 0.f;
        y.z = y.z > 0.f ? y.z : 0.f;
        y.w = y.w > 0.f ? y.w : 0.f;
        *(float4*)&out[(size_t)m * COUT + c4] = y;
    }
}

extern "C" void kernel_launch(void* const* d_in, const int* in_sizes, int n_in,
                              void* d_out, int out_size, void* d_ws, size_t ws_size,
                              hipStream_t stream)
{
    const float* feats  = (const float*)d_in[0];
    const float* Wc     = (const float*)d_in[1];
    const float* Wsk    = (const float*)d_in[2];
    const float* gamma  = (const float*)d_in[3];
    const float* beta   = (const float*)d_in[4];
    const float* sgamma = (const float*)d_in[5];
    const float* sbeta  = (const float*)d_in[6];
    const float* fc1    = (const float*)d_in[7];
    const float* fc2    = (const float*)d_in[8];
    const int* cin_idx  = (const int*)d_in[9];
    const int* cout_idx = (const int*)d_in[10];
    const int* sin_idx  = (const int*)d_in[11];
    const int* sout_idx = (const int*)d_in[12];
    const int* boo      = (const int*)d_in[13];

    const int N  = in_sizes[0] / CIN;
    const int P  = in_sizes[9] / 9;
    const int Ls = in_sizes[11];
    const int M  = in_sizes[13];

    float* out = (float*)d_out;

    // workspace layout
    char* ws = (char*)d_ws;
    __bf16* fb = (__bf16*)ws;                       // (N+1) x CIN bf16
    size_t off = (size_t)(N + 1) * CIN * sizeof(__bf16);
    off = (off + 255) & ~(size_t)255;
    __bf16* wfrag = (__bf16*)(ws + off);
    off += (size_t)160 * 64 * 8 * sizeof(__bf16);
    off = (off + 255) & ~(size_t)255;
    int* tap_in = (int*)(ws + off);                 // 9 x M
    off += (size_t)9 * M * sizeof(int);
    off = (off + 255) & ~(size_t)255;
    float* G = (float*)(ws + off);                  // Ls x COUT
    off += (size_t)Ls * COUT * sizeof(float);
    int* inv_skip = (int*)(ws + off);               // M
    off += (size_t)M * sizeof(int);
    off = (off + 255) & ~(size_t)255;
    float* stats = (float*)(ws + off);              // NB x 640 (skip buckets)
    off += (size_t)NB * 640 * sizeof(float);
    float* gstats = (float*)(ws + off);             // NBLK x 384 (conv slots)
    off += (size_t)NBLK * 384 * sizeof(float);
    float* gsum = (float*)(ws + off);               // 384
    off += 384 * sizeof(float);
    int* msplit = (int*)(ws + off);
    off += 256;
    float* params = (float*)(ws + off);
    float* scale = params, *shift = params + 128;
    float* sscale = params + 256, *sshift = params + 384, *attn = params + 512;

    hipMemsetAsync(stats, 0, (size_t)NB * 640 * sizeof(float), stream);
    hipMemsetAsync(inv_skip, 0xFF, (size_t)M * sizeof(int), stream);   // -1
    hipMemsetAsync(fb + (size_t)N * CIN, 0, CIN * sizeof(__bf16), stream);

    const int total8 = N * CIN / 8;
    prep_feats_kernel<<<(total8 + 255) / 256, 256, 0, stream>>>(feats, fb, total8);
    prep_wfrag_kernel<<<(160 * 64 + 255) / 256, 256, 0, stream>>>(Wc, Wsk, wfrag);

    const int ttotal = 9 * M;
    tap_fill_kernel<<<(ttotal + 255) / 256, 256, 0, stream>>>(tap_in, msplit, boo, ttotal, N, M);
    tap_scatter_kernel<<<dim3((P + 255) / 256, 9), 256, 0, stream>>>(cin_idx, cout_idx, tap_in, P, M);
    inv_kernel<<<(Ls + 255) / 256, 256, 0, stream>>>(sout_idx, inv_skip, Ls);

    const int njobs = (M + 15) >> 4;
    const int jpb = (njobs + NBLK - 1) / NBLK;
    conv_mfma_kernel<<<NBLK, 256, 0, stream>>>(
        fb, wfrag, tap_in, msplit, out, gstats, N, M, njobs, jpb);

    skip_mfma_kernel<<<256, 256, 0, stream>>>(
        fb, wfrag, sin_idx, G, stats, Ls);

    reduce_gstats_kernel<<<384, 256, 0, stream>>>(gstats, gsum, NBLK);

    params_kernel<<<1, 128, 0, stream>>>(
        gsum, stats, msplit, gamma, beta, sgamma, sbeta, fc1, fc2,
        scale, shift, sscale, sshift, attn, Ls, M);

    final_kernel<<<2048, 256, 0, stream>>>(
        out, G, inv_skip, boo, scale, shift, sscale, sshift, attn, M);
}

// Round 7
// 334.896 us; speedup vs baseline: 3.9450x; 3.9450x over previous
//
#include <hip/hip_runtime.h>

#define CIN 64
#define COUT 128
#define NB 32        // skip-stat buckets

typedef __bf16 bf16x8 __attribute__((ext_vector_type(8)));
typedef float  f32x4  __attribute__((ext_vector_type(4)));

// ---------------------------------------------------------------------------
// Prep: features fp32 -> bf16 rows.
// ---------------------------------------------------------------------------
__global__ __launch_bounds__(256) void prep_feats_kernel(
    const float* __restrict__ feats, __bf16* __restrict__ fb, int total8)
{
    const int i = blockIdx.x * 256 + threadIdx.x;
    if (i >= total8) return;
    const int i8 = i * 8;
    const float4 x0 = *(const float4*)(feats + i8);
    const float4 x1 = *(const float4*)(feats + i8 + 4);
    bf16x8 v;
    v[0] = (__bf16)x0.x; v[1] = (__bf16)x0.y; v[2] = (__bf16)x0.z; v[3] = (__bf16)x0.w;
    v[4] = (__bf16)x1.x; v[5] = (__bf16)x1.y; v[6] = (__bf16)x1.z; v[7] = (__bf16)x1.w;
    *(bf16x8*)(fb + i8) = v;
}

// ---------------------------------------------------------------------------
// Prep: pack W_conv (9 taps) + W_skip into MFMA B-fragment layout.
// Frag f: tap f/16 (f<144), skip otherwise; rem: c=rem>>1 (col-tile), s=rem&1.
// Lane l holds B[s*32+(l>>4)*8+j][c*16+(l&15)], j=0..7.
// ---------------------------------------------------------------------------
__global__ __launch_bounds__(256) void prep_wfrag_kernel(
    const float* __restrict__ Wc, const float* __restrict__ Ws,
    __bf16* __restrict__ wf)
{
    const int id = blockIdx.x * 256 + threadIdx.x;
    if (id >= 160 * 64) return;
    const int f = id >> 6, lane = id & 63;
    const float* W;
    int r;
    if (f < 144) { W = Wc + (size_t)(f >> 4) * CIN * COUT; r = f & 15; }
    else         { W = Ws;                                  r = f - 144; }
    const int c = r >> 1, s = r & 1;
    const int kbase = s * 32 + (lane >> 4) * 8;
    const int col = c * 16 + (lane & 15);
    bf16x8 v;
#pragma unroll
    for (int j = 0; j < 8; ++j) v[j] = (__bf16)W[(size_t)(kbase + j) * COUT + col];
    *(bf16x8*)(wf + ((size_t)f * 64 + lane) * 8) = v;
}

// ---------------------------------------------------------------------------
// tap_in fill (= N sentinel) + m_split (batch boundary).
// ---------------------------------------------------------------------------
__global__ __launch_bounds__(256) void tap_fill_kernel(
    int* __restrict__ tap_in, int* __restrict__ msplit,
    const int* __restrict__ boo, int total, int N, int M)
{
    const int id = blockIdx.x * 256 + threadIdx.x;
    if (id < total) tap_in[id] = N;
    if (id == 0) {
        int lo = 0, hi = M;
        while (lo < hi) { const int mid = (lo + hi) >> 1; if (boo[mid] < 1) lo = mid + 1; else hi = mid; }
        msplit[0] = lo;
    }
}

__global__ __launch_bounds__(256) void tap_scatter_kernel(
    const int* __restrict__ cin_idx, const int* __restrict__ cout_idx,
    int* __restrict__ tap_in, int P, int M)
{
    const int e = blockIdx.x * 256 + threadIdx.x;
    const int k = blockIdx.y;
    if (e >= P) return;
    const int oo = cout_idx[(size_t)k * P + e];
    if (oo < M) tap_in[(size_t)k * M + oo] = cin_idx[(size_t)k * P + e];
}

__global__ __launch_bounds__(256) void inv_kernel(
    const int* __restrict__ sout, int* __restrict__ inv, int Ls)
{
    const int i = blockIdx.x * 256 + threadIdx.x;
    if (i < Ls) inv[sout[i]] = i;
}

// ---------------------------------------------------------------------------
// Conv: block owns 64 contiguous rows; 4 col-split waves (32 cols each).
// Per wave: for k: load 4 B-frags once; 4 row-groups: gather A, MFMA into D.
// Epilogue: D -> LDS tile (disjoint), coalesced block store + fused BN stats.
// B-table (160KB) stays L2-resident: read once per tap per block.
// ---------------------------------------------------------------------------
__global__ __launch_bounds__(256, 4) void conv_mfma_kernel(
    const __bf16* __restrict__ fb,      // [N+1][CIN], row N = zeros
    const __bf16* __restrict__ wf,
    const int* __restrict__ tap_in,     // [9][M]
    const int* __restrict__ msplit_p,
    float* __restrict__ out,
    float* __restrict__ gstats,         // [ntiles][384]
    int N, int M)
{
    __shared__ float acc[64 * COUT];    // 32 KB
    __shared__ float sred[384];
    const int t = threadIdx.x, lane = t & 63, wv = t >> 6;
    const int arow = lane & 15, apart = lane >> 4;
    const int m0 = blockIdx.x * 64;
    const int msplit = msplit_p[0];

    for (int i = t; i < 384; i += 256) sred[i] = 0.f;

    f32x4 D[4][2];
#pragma unroll
    for (int g = 0; g < 4; ++g) {
        D[g][0] = (f32x4){0.f, 0.f, 0.f, 0.f};
        D[g][1] = (f32x4){0.f, 0.f, 0.f, 0.f};
    }

#pragma unroll
    for (int k = 0; k < 9; ++k) {
        const __bf16* wb = wf + ((size_t)((k * 16 + wv * 4) * 64) + lane) * 8;
        const bf16x8 b00 = *(const bf16x8*)(wb + 0 * 512);  // ctile wv*2+0, k0
        const bf16x8 b01 = *(const bf16x8*)(wb + 1 * 512);  // ctile wv*2+0, k1
        const bf16x8 b10 = *(const bf16x8*)(wb + 2 * 512);  // ctile wv*2+1, k0
        const bf16x8 b11 = *(const bf16x8*)(wb + 3 * 512);  // ctile wv*2+1, k1
        const int* __restrict__ tk = tap_in + (size_t)k * M;
#pragma unroll
        for (int g = 0; g < 4; ++g) {
            const int mr = m0 + g * 16 + arow;
            const int idx = (mr < M) ? tk[mr] : N;
            const __bf16* f0 = fb + (size_t)idx * CIN + apart * 8;
            const bf16x8 a0 = *(const bf16x8*)f0;
            const bf16x8 a1 = *(const bf16x8*)(f0 + 32);
            D[g][0] = __builtin_amdgcn_mfma_f32_16x16x32_bf16(a0, b00, D[g][0], 0, 0, 0);
            D[g][0] = __builtin_amdgcn_mfma_f32_16x16x32_bf16(a1, b01, D[g][0], 0, 0, 0);
            D[g][1] = __builtin_amdgcn_mfma_f32_16x16x32_bf16(a0, b10, D[g][1], 0, 0, 0);
            D[g][1] = __builtin_amdgcn_mfma_f32_16x16x32_bf16(a1, b11, D[g][1], 0, 0, 0);
        }
    }

    // scatter D to LDS (disjoint per wave): row=g*16+apart*4+j, col=wv*32+c*16+arow
#pragma unroll
    for (int g = 0; g < 4; ++g)
#pragma unroll
        for (int c = 0; c < 2; ++c)
#pragma unroll
            for (int j = 0; j < 4; ++j)
                acc[(g * 16 + apart * 4 + j) * COUT + wv * 32 + c * 16 + arow] = D[g][c][j];
    __syncthreads();

    // coalesced store (8 rows x 512B per inst) + fused BN stats
    const int c4 = (t & 31) * 4;
    const int r0 = t >> 5;
    float st_s[4] = {0.f, 0.f, 0.f, 0.f};
    float st_q[4] = {0.f, 0.f, 0.f, 0.f};
    float st_0[4] = {0.f, 0.f, 0.f, 0.f};
#pragma unroll
    for (int i = 0; i < 8; ++i) {
        const int r = r0 + i * 8;
        const int m = m0 + r;
        if (m < M) {
            const f32x4 v = *(const f32x4*)&acc[r * COUT + c4];
            *(f32x4*)(out + (size_t)m * COUT + c4) = v;
            const bool b0 = m < msplit;
#pragma unroll
            for (int cc = 0; cc < 4; ++cc) {
                st_s[cc] += v[cc];
                st_q[cc] += v[cc] * v[cc];
                if (b0) st_0[cc] += v[cc];
            }
        }
    }
#pragma unroll
    for (int cc = 0; cc < 4; ++cc) {
        atomicAdd(&sred[c4 + cc],       st_0[cc]);
        atomicAdd(&sred[128 + c4 + cc], st_s[cc] - st_0[cc]);
        atomicAdd(&sred[256 + c4 + cc], st_q[cc]);
    }
    __syncthreads();
    if (t < 128) {
        float* gs = gstats + (size_t)blockIdx.x * 384;
        gs[t]       = sred[t];
        gs[128 + t] = sred[128 + t];
        gs[256 + t] = sred[256 + t];
    }
}

// ---------------------------------------------------------------------------
// Reduce gstats[nblk][384] -> gsum[384].
// ---------------------------------------------------------------------------
__global__ __launch_bounds__(256) void reduce_gstats_kernel(
    const float* __restrict__ gstats, float* __restrict__ gsum, int nblk)
{
    __shared__ float red[256];
    const int sc = blockIdx.x;
    float s = 0.f;
    for (int b = threadIdx.x; b < nblk; b += 256) s += gstats[(size_t)b * 384 + sc];
    red[threadIdx.x] = s;
    __syncthreads();
    for (int st = 128; st > 0; st >>= 1) {
        if (threadIdx.x < st) red[threadIdx.x] += red[threadIdx.x + st];
        __syncthreads();
    }
    if (threadIdx.x == 0) gsum[sc] = red[0];
}

// ---------------------------------------------------------------------------
// Skip path via MFMA, column-split waves, bucketed stat atomics.
// ---------------------------------------------------------------------------
__global__ __launch_bounds__(256, 2) void skip_mfma_kernel(
    const __bf16* __restrict__ fb, const __bf16* __restrict__ wf,
    const int* __restrict__ sin_idx,
    float* __restrict__ G, float* __restrict__ stats, int Ls)
{
    __shared__ float sk[2][COUT];
    const int t = threadIdx.x, lane = t & 63, wv = t >> 6;
    const int arow = lane & 15, apart = lane >> 4;

    const __bf16* wk = wf + ((size_t)144 * 64 + lane) * 8;
    const bf16x8 b00 = *(const bf16x8*)(wk + (size_t)(wv * 4 + 0) * 512);
    const bf16x8 b01 = *(const bf16x8*)(wk + (size_t)(wv * 4 + 1) * 512);
    const bf16x8 b10 = *(const bf16x8*)(wk + (size_t)(wv * 4 + 2) * 512);
    const bf16x8 b11 = *(const bf16x8*)(wk + (size_t)(wv * 4 + 3) * 512);
    const int colA = wv * 32 + arow;
    const int colB = colA + 16;

    float s1A = 0.f, s2A = 0.f, s1B = 0.f, s2B = 0.f;
    const int ngroups = (Ls + 15) >> 4;
    for (int g = blockIdx.x; g < ngroups; g += gridDim.x) {
        const int e0 = g * 16;
        const int ea = e0 + arow;
        const int ii = (ea < Ls) ? sin_idx[ea] : 0;
        const __bf16* fr = fb + (size_t)ii * CIN + apart * 8;
        const bf16x8 a0 = *(const bf16x8*)fr;
        const bf16x8 a1 = *(const bf16x8*)(fr + 32);

        f32x4 dA = {0.f,0.f,0.f,0.f};
        f32x4 dB = {0.f,0.f,0.f,0.f};
        dA = __builtin_amdgcn_mfma_f32_16x16x32_bf16(a0, b00, dA, 0, 0, 0);
        dA = __builtin_amdgcn_mfma_f32_16x16x32_bf16(a1, b01, dA, 0, 0, 0);
        dB = __builtin_amdgcn_mfma_f32_16x16x32_bf16(a0, b10, dB, 0, 0, 0);
        dB = __builtin_amdgcn_mfma_f32_16x16x32_bf16(a1, b11, dB, 0, 0, 0);

        const int er = e0 + apart * 4;
#pragma unroll
        for (int j = 0; j < 4; ++j) {
            if (er + j < Ls) {
                const float vA = dA[j], vB = dB[j];
                G[(size_t)(er + j) * COUT + colA] = vA;
                G[(size_t)(er + j) * COUT + colB] = vB;
                s1A += vA; s2A += vA * vA;
                s1B += vB; s2B += vB * vB;
            }
        }
    }
    s1A += __shfl_xor(s1A, 16); s1A += __shfl_xor(s1A, 32);
    s2A += __shfl_xor(s2A, 16); s2A += __shfl_xor(s2A, 32);
    s1B += __shfl_xor(s1B, 16); s1B += __shfl_xor(s1B, 32);
    s2B += __shfl_xor(s2B, 16); s2B += __shfl_xor(s2B, 32);
    if (apart == 0) {
        sk[0][colA] = s1A; sk[0][colB] = s1B;
        sk[1][colA] = s2A; sk[1][colB] = s2B;
    }
    __syncthreads();
    float* bucket = stats + (size_t)(blockIdx.x & (NB - 1)) * 640;
    if (t < 128) {
        atomicAdd(&bucket[384 + t], sk[0][t]);
        atomicAdd(&bucket[512 + t], sk[1][t]);
    }
}

// ---------------------------------------------------------------------------
// Single-block: combine gsum + skip buckets, BN params, SE MLP.
// ---------------------------------------------------------------------------
__global__ __launch_bounds__(128) void params_kernel(
    const float* __restrict__ gsum,
    const float* __restrict__ stats,
    const int* __restrict__ msplit_p,
    const float* __restrict__ gamma, const float* __restrict__ beta,
    const float* __restrict__ sgamma, const float* __restrict__ sbeta,
    const float* __restrict__ fc1, const float* __restrict__ fc2,
    float* __restrict__ scale, float* __restrict__ shift,
    float* __restrict__ sscale, float* __restrict__ sshift,
    float* __restrict__ attn,
    int Ls, int M)
{
    __shared__ float desc[2][COUT];
    __shared__ float hid[2][8];
    const int ch = threadIdx.x;

    const float s0 = gsum[ch], s1 = gsum[128 + ch], q = gsum[256 + ch];
    float ss = 0.f, sq = 0.f;
    for (int b = 0; b < NB; ++b) {
        const float* st = stats + (size_t)b * 640;
        ss += st[384 + ch]; sq += st[512 + ch];
    }

    const float c0 = (float)msplit_p[0], c1 = (float)M - c0;
    const float Mf = (float)M;
    const float mu  = (s0 + s1) / Mf;
    const float var = q / Mf - mu * mu;
    const float rs  = rsqrtf(var + 1e-5f);
    const float sc  = rs * gamma[ch];
    const float sh  = beta[ch] - mu * sc;
    scale[ch] = sc;
    shift[ch] = sh;
    desc[0][ch] = (s0 / c0) * sc + sh;
    desc[1][ch] = (s1 / c1) * sc + sh;

    const float lsf  = (float)Ls;
    const float mus  = ss / lsf;
    const float vars = sq / lsf - mus * mus;
    const float rss  = rsqrtf(vars + 1e-5f);
    const float ssc  = rss * sgamma[ch];
    sscale[ch] = ssc;
    sshift[ch] = sbeta[ch] - mus * ssc;

    __syncthreads();
    if (ch < 16) {
        const int b = ch >> 3, h = ch & 7;
        float a = 0.f;
        for (int c = 0; c < COUT; ++c) a += desc[b][c] * fc1[c * 8 + h];
        hid[b][h] = fmaxf(a, 0.f);
    }
    __syncthreads();
    for (int b = 0; b < 2; ++b) {
        float a = 0.f;
        for (int h = 0; h < 8; ++h) a += hid[b][h] * fc2[h * COUT + ch];
        attn[b * COUT + ch] = 1.f / (1.f + expf(-a));
    }
}

// ---------------------------------------------------------------------------
// Epilogue: out = relu(bn(x)*attn[b] + bn_skip(G[inv])), float4-vectorized.
// ---------------------------------------------------------------------------
__global__ __launch_bounds__(256) void final_kernel(
    float* __restrict__ out,
    const float* __restrict__ G,
    const int* __restrict__ inv_skip,
    const int* __restrict__ batch_of_out,
    const float* __restrict__ scale, const float* __restrict__ shift,
    const float* __restrict__ sscale, const float* __restrict__ sshift,
    const float* __restrict__ attn,
    int M)
{
    const int t  = threadIdx.x;
    const int c4 = (t & 31) * 4;
    const int rw = t >> 5;
    const float4 sc  = *(const float4*)&scale[c4];
    const float4 sh  = *(const float4*)&shift[c4];
    const float4 ssc = *(const float4*)&sscale[c4];
    const float4 ssh = *(const float4*)&sshift[c4];
    const float4 at0 = *(const float4*)&attn[c4];
    const float4 at1 = *(const float4*)&attn[COUT + c4];

    for (int m = blockIdx.x * 8 + rw; m < M; m += gridDim.x * 8) {
        const float4 x = *(const float4*)&out[(size_t)m * COUT + c4];
        const int b = batch_of_out[m];
        const int j = inv_skip[m];
        const float4 av = b ? at1 : at0;
        float4 y;
        y.x = (x.x * sc.x + sh.x) * av.x;
        y.y = (x.y * sc.y + sh.y) * av.y;
        y.z = (x.z * sc.z + sh.z) * av.z;
        y.w = (x.w * sc.w + sh.w) * av.w;
        if (j >= 0) {
            const float4 g = *(const float4*)&G[(size_t)j * COUT + c4];
            y.x += g.x * ssc.x + ssh.x;
            y.y += g.y * ssc.y + ssh.y;
            y.z += g.z * ssc.z + ssh.z;
            y.w += g.w * ssc.w + ssh.w;
        }
        y.x = y.x > 0.f ? y.x : 0.f;
        y.y = y.y > 0.f ? y.y : 0.f;
        y.z = y.z > 0.f ? y.z : 0.f;
        y.w = y.w > 0.f ? y.w : 0.f;
        *(float4*)&out[(size_t)m * COUT + c4] = y;
    }
}

extern "C" void kernel_launch(void* const* d_in, const int* in_sizes, int n_in,
                              void* d_out, int out_size, void* d_ws, size_t ws_size,
                              hipStream_t stream)
{
    const float* feats  = (const float*)d_in[0];
    const float* Wc     = (const float*)d_in[1];
    const float* Wsk    = (const float*)d_in[2];
    const float* gamma  = (const float*)d_in[3];
    const float* beta   = (const float*)d_in[4];
    const float* sgamma = (const float*)d_in[5];
    const float* sbeta  = (const float*)d_in[6];
    const float* fc1    = (const float*)d_in[7];
    const float* fc2    = (const float*)d_in[8];
    const int* cin_idx  = (const int*)d_in[9];
    const int* cout_idx = (const int*)d_in[10];
    const int* sin_idx  = (const int*)d_in[11];
    const int* sout_idx = (const int*)d_in[12];
    const int* boo      = (const int*)d_in[13];

    const int N  = in_sizes[0] / CIN;
    const int P  = in_sizes[9] / 9;
    const int Ls = in_sizes[11];
    const int M  = in_sizes[13];
    const int ntiles = (M + 63) / 64;

    float* out = (float*)d_out;

    // workspace layout
    char* ws = (char*)d_ws;
    __bf16* fb = (__bf16*)ws;                       // (N+1) x CIN bf16
    size_t off = (size_t)(N + 1) * CIN * sizeof(__bf16);
    off = (off + 255) & ~(size_t)255;
    __bf16* wfrag = (__bf16*)(ws + off);
    off += (size_t)160 * 64 * 8 * sizeof(__bf16);
    off = (off + 255) & ~(size_t)255;
    int* tap_in = (int*)(ws + off);                 // 9 x M
    off += (size_t)9 * M * sizeof(int);
    off = (off + 255) & ~(size_t)255;
    float* G = (float*)(ws + off);                  // Ls x COUT
    off += (size_t)Ls * COUT * sizeof(float);
    int* inv_skip = (int*)(ws + off);               // M
    off += (size_t)M * sizeof(int);
    off = (off + 255) & ~(size_t)255;
    float* stats = (float*)(ws + off);              // NB x 640 (skip buckets)
    off += (size_t)NB * 640 * sizeof(float);
    float* gstats = (float*)(ws + off);             // ntiles x 384 (conv slots)
    off += (size_t)ntiles * 384 * sizeof(float);
    float* gsum = (float*)(ws + off);               // 384
    off += 384 * sizeof(float);
    int* msplit = (int*)(ws + off);
    off += 256;
    float* params = (float*)(ws + off);
    float* scale = params, *shift = params + 128;
    float* sscale = params + 256, *sshift = params + 384, *attn = params + 512;

    hipMemsetAsync(stats, 0, (size_t)NB * 640 * sizeof(float), stream);
    hipMemsetAsync(inv_skip, 0xFF, (size_t)M * sizeof(int), stream);   // -1
    hipMemsetAsync(fb + (size_t)N * CIN, 0, CIN * sizeof(__bf16), stream);

    const int total8 = N * CIN / 8;
    prep_feats_kernel<<<(total8 + 255) / 256, 256, 0, stream>>>(feats, fb, total8);
    prep_wfrag_kernel<<<(160 * 64 + 255) / 256, 256, 0, stream>>>(Wc, Wsk, wfrag);

    const int ttotal = 9 * M;
    tap_fill_kernel<<<(ttotal + 255) / 256, 256, 0, stream>>>(tap_in, msplit, boo, ttotal, N, M);
    tap_scatter_kernel<<<dim3((P + 255) / 256, 9), 256, 0, stream>>>(cin_idx, cout_idx, tap_in, P, M);
    inv_kernel<<<(Ls + 255) / 256, 256, 0, stream>>>(sout_idx, inv_skip, Ls);

    conv_mfma_kernel<<<ntiles, 256, 0, stream>>>(
        fb, wfrag, tap_in, msplit, out, gstats, N, M);

    skip_mfma_kernel<<<256, 256, 0, stream>>>(
        fb, wfrag, sin_idx, G, stats, Ls);

    reduce_gstats_kernel<<<384, 256, 0, stream>>>(gstats, gsum, ntiles);

    params_kernel<<<1, 128, 0, stream>>>(
        gsum, stats, msplit, gamma, beta, sgamma, sbeta, fc1, fc2,
        scale, shift, sscale, sshift, attn, Ls, M);

    final_kernel<<<2048, 256, 0, stream>>>(
        out, G, inv_skip, boo, scale, shift, sscale, sshift, attn, M);
}